// Round 9
// baseline (1097.408 us; speedup 1.0000x reference)
//
#include <hip/hip_runtime.h>

#define H 96
#define W 96
#define CIN 1024
#define NPIX 9216          // 96*96
#define NCH 54             // 18 cls + 36 reg channels
#define NA 82944           // 9216*9 anchors
#define TOPN 6000
#define NW 94              // ceil(6000/64)
#define POSN 300
#define CAND_CAP 8192

typedef _Float16 half8_t __attribute__((ext_vector_type(8)));
typedef float f32x4 __attribute__((ext_vector_type(4)));

#define CIP 40             // padded ci stride in halves (80 B: 16B-aligned, 2-way banks = free)
#define XS_PLANE 11760     // 3*98*40 halves
#define HP_HALF 4718592    // 4*9216*128 floats per K-split buffer

// ---------------------------------------------------------------------------
// init: hist/ctrl <- 0
// ---------------------------------------------------------------------------
__global__ void k_init(unsigned int* __restrict__ hist, unsigned int* __restrict__ ctrl) {
    int t = blockIdx.x * 256 + threadIdx.x;
    if (t < 65536) hist[t] = 0u;
    else if (t < 65536 + 16) ctrl[t - 65536] = 0u;
}

// ---------------------------------------------------------------------------
// x transpose + fp16 split: x[ci][px] fp32 -> xt_h[px][ci], xt_l[px][ci]
// half8 (16B/lane) vectorized stores.
// ---------------------------------------------------------------------------
__global__ __launch_bounds__(256) void k_xtr(const float* __restrict__ x,
                                             _Float16* __restrict__ xh,
                                             _Float16* __restrict__ xl) {
    __shared__ float t[64 * 65];
    const int tid = threadIdx.x;
    const int px0 = blockIdx.x * 64, ci0 = blockIdx.y * 64;
    for (int i = tid; i < 4096; i += 256) {
        int ci = i >> 6, px = i & 63;
        t[ci * 65 + px] = x[(size_t)(ci0 + ci) * NPIX + px0 + px];
    }
    __syncthreads();
    for (int i = tid; i < 512; i += 256) {     // 64 px x 8 ci-octets
        int px = i >> 3, q = i & 7;
        _Float16 h8[8], l8[8];
#pragma unroll
        for (int j = 0; j < 8; ++j) {
            float v = t[(q * 8 + j) * 65 + px];
            _Float16 h = (_Float16)v;
            h8[j] = h;
            l8[j] = (_Float16)((v - (float)h) * 2048.f);
        }
        size_t o = (size_t)(px0 + px) * 1024 + ci0 + q * 8;
        *(half8_t*)(xh + o) = *(half8_t*)h8;
        *(half8_t*)(xl + o) = *(half8_t*)l8;
    }
}

// ---------------------------------------------------------------------------
// weight transform to MFMA-fragment order + fp16 split (coalesced, R8).
// ---------------------------------------------------------------------------
__global__ __launch_bounds__(256) void k_wtr(const float* __restrict__ wr,
                                             _Float16* __restrict__ wt2) {
    __shared__ float tile[32 * 292];
    const int cb = blockIdx.x, cc = blockIdx.y;
    const int tid = threadIdx.x;
    for (int g = 0; g < 4; ++g) {
        __syncthreads();
        for (int i = tid; i < 32 * 288; i += 256) {
            int row = i / 288, col = i - row * 288;
            tile[row * 292 + col] = wr[(size_t)(cb * 128 + g * 32 + row) * 9216 + cc * 288 + col];
        }
        __syncthreads();
#pragma unroll
        for (int k = 0; k < 9; ++k) {
            int G = k * 256 + tid;           // < 2304
            int tap = G >> 8, r = G & 255;
            int pl = r >> 7, ntl = (r >> 6) & 1, l = r & 63;
            int co_loc = ntl * 16 + (l & 15);
            int ci_b = (l >> 4) * 8;
            _Float16 o8[8];
#pragma unroll
            for (int j = 0; j < 8; ++j) {
                float v = tile[co_loc * 292 + (ci_b + j) * 9 + tap];
                _Float16 h = (_Float16)v;
                o8[j] = pl ? (_Float16)((v - (float)h) * 2048.f) : h;
            }
            _Float16* dst = wt2 + ((size_t)((tap * 4 + cb) * 32 + cc)) * 8192 +
                            (size_t)(pl * 8 + (g * 2 + ntl)) * 512 + l * 8;
            *(half8_t*)dst = *(half8_t*)o8;
        }
    }
}

// ---------------------------------------------------------------------------
// MFMA implicit-GEMM conv3x3(1024->512), K-split by 2.
// fp16 2-plane split: h = Ah*Bh + (Ah*Bl' + Al'*Bh)/2048.
// Block = 1 row (96 px) x 128 co, 4 waves; wave = 3 m-tiles x 4 n-tiles.
// B direct from global (fragment-ordered wt2), pipelined TWO taps deep
// (buffers indexed by compile-time parity; chunks processed in pairs so the
// odd-9-taps parity flip stays constexpr). x register-prefetched one chunk
// ahead. 2 blocks/CU.
// ---------------------------------------------------------------------------
__global__ __launch_bounds__(256, 2) void k_conv(
    const _Float16* __restrict__ xth, const _Float16* __restrict__ xtl,
    const _Float16* __restrict__ wt2, float* __restrict__ hp) {
    __shared__ __align__(16) char smem[49408];   // xs 47040 B; epilogue 96x128 f32
    _Float16* xs = (_Float16*)smem;

    const int tid = threadIdx.x;
    const int cb = blockIdx.x;        // co block of 128
    const int y  = blockIdx.y;        // output row
    const int ks = blockIdx.z;        // K-split half
    const int l  = tid & 63;
    const int wv = tid >> 6;          // 0..3
    const int mg = wv & 1;            // m-group
    const int ng = wv >> 1;           // n-group
    const int lm = l & 15;
    const int lk = l >> 4;            // 0..3

    f32x4 acc_h[3][4];
    f32x4 acc_x[3][4];
#pragma unroll
    for (int m2 = 0; m2 < 3; ++m2)
#pragma unroll
        for (int nt = 0; nt < 4; ++nt) {
            acc_h[m2][nt] = (f32x4){0.f, 0.f, 0.f, 0.f};
            acc_x[m2][nt] = (f32x4){0.f, 0.f, 0.f, 0.f};
        }

    // zero px pad columns (pxp = 0 and 97), both planes, 3 rows
    for (int i = tid; i < 480; i += 256) {
        int pl = i / 240, j = i - pl * 240;
        int r = j / 80, j2 = j - r * 80;
        int side = j2 / 40, c = j2 - side * 40;
        xs[pl * XS_PLANE + (r * 98 + side * 97) * CIP + c] = (_Float16)0.f;
    }

    auto ldx = [&](float4* xr, int cc_) {
#pragma unroll
        for (int k = 0; k < 9; ++k) {
            int item = k * 256 + tid;
            int pl = (item >= 1152) ? 1 : 0;
            int j = item - pl * 1152;
            int r = j / 384, j2 = j - r * 384;
            int px = j2 >> 2, q = j2 & 3;
            int yy = y + r - 1;
            float4 v = {0.f, 0.f, 0.f, 0.f};
            if (yy >= 0 && yy < H)
                v = *(const float4*)((pl ? xtl : xth) + (size_t)(yy * 96 + px) * 1024 + cc_ * 32 + q * 8);
            xr[k] = v;
        }
    };
    auto stx = [&](const float4* xr) {
#pragma unroll
        for (int k = 0; k < 9; ++k) {
            int item = k * 256 + tid;
            int pl = (item >= 1152) ? 1 : 0;
            int j = item - pl * 1152;
            int r = j / 384, j2 = j - r * 384;
            int px = j2 >> 2, q = j2 & 3;
            *(float4*)(xs + pl * XS_PLANE + (r * 98 + px + 1) * CIP + q * 8) = xr[k];
        }
    };
    auto ldb = [&](half8_t* bh, half8_t* bl, int cc_, int tap_) {
        const _Float16* base = wt2 + ((size_t)((tap_ * 4 + cb) * 32 + cc_) * 16) * 512 + (size_t)l * 8;
#pragma unroll
        for (int nt = 0; nt < 4; ++nt) {
            bh[nt] = *(const half8_t*)(base + (size_t)(ng * 4 + nt) * 512);
            bl[nt] = *(const half8_t*)(base + (size_t)(8 + ng * 4 + nt) * 512);
        }
    };

    const int cc0 = ks * 16;
    float4 xr[9];
    ldx(xr, cc0);
    half8_t bbh[2][4], bbl[2][4];
    ldb(bbh[0], bbl[0], cc0, 0);     // T = 0 (parity 0)
    ldb(bbh[1], bbl[1], cc0, 1);     // T = 1 (parity 1)

    auto chunk_body = [&](int cc, int par0) {
        __syncthreads();           // previous chunk's xs reads complete
        stx(xr);
        __syncthreads();           // xs visible
        const int ccn = (cc + 1 < 32) ? cc + 1 : cc;
        ldx(xr, ccn);              // prefetch next chunk's x

#pragma unroll
        for (int tap = 0; tap < 9; ++tap) {
            const int bi = (tap + par0) & 1;        // compile-time after unroll
            const int ky = tap / 3, kx = tap - 3 * (tap / 3);
            half8_t ah[3], al[3];
#pragma unroll
            for (int m2 = 0; m2 < 3; ++m2) {
                const int pxp = (mg * 3 + m2) * 16 + lm + kx;
                ah[m2] = *(const half8_t*)(xs + (ky * 98 + pxp) * CIP + lk * 8);
                al[m2] = *(const half8_t*)(xs + XS_PLANE + (ky * 98 + pxp) * CIP + lk * 8);
            }
#pragma unroll
            for (int m2 = 0; m2 < 3; ++m2)
#pragma unroll
                for (int nt = 0; nt < 4; ++nt)
                    acc_h[m2][nt] = __builtin_amdgcn_mfma_f32_16x16x32_f16(ah[m2], bbh[bi][nt], acc_h[m2][nt], 0, 0, 0);
#pragma unroll
            for (int m2 = 0; m2 < 3; ++m2)
#pragma unroll
                for (int nt = 0; nt < 4; ++nt)
                    acc_x[m2][nt] = __builtin_amdgcn_mfma_f32_16x16x32_f16(ah[m2], bbl[bi][nt], acc_x[m2][nt], 0, 0, 0);
#pragma unroll
            for (int m2 = 0; m2 < 3; ++m2)
#pragma unroll
                for (int nt = 0; nt < 4; ++nt)
                    acc_x[m2][nt] = __builtin_amdgcn_mfma_f32_16x16x32_f16(al[m2], bbh[bi][nt], acc_x[m2][nt], 0, 0, 0);
            // refill just-freed buffer with tap+2 (two-deep pipeline)
            int pt = tap + 2, pcc = cc;
            if (pt > 8) { pt -= 9; pcc = cc + 1; if (pcc > 31) pcc = 31; }
            ldb(bbh[bi], bbl[bi], pcc, pt);
        }
    };

    for (int cp = 0; cp < 8; ++cp) {
        chunk_body(cc0 + 2 * cp, 0);
        chunk_body(cc0 + 2 * cp + 1, 1);   // 9 taps flip parity each chunk
    }

    // ---- epilogue: combine planes, bounce through LDS, coalesced store ----
    __syncthreads();
    float* cs = (float*)smem;
#pragma unroll
    for (int m2 = 0; m2 < 3; ++m2)
#pragma unroll
        for (int nt = 0; nt < 4; ++nt) {
            int co = (ng * 4 + nt) * 16 + lm;
#pragma unroll
            for (int r = 0; r < 4; ++r) {
                int px = (mg * 3 + m2) * 16 + lk * 4 + r;
                cs[px * 128 + co] = acc_h[m2][nt][r] + acc_x[m2][nt][r] * (1.f / 2048.f);
            }
        }
    __syncthreads();
    float4* dst = (float4*)(hp + ((size_t)(ks * 4 + cb) * NPIX + y * 96) * 128);
    const float4* src = (const float4*)cs;
    for (int i = tid; i < 3072; i += 256) dst[i] = src[i];
}

// ---------------------------------------------------------------------------
// post: h = relu(hp0+hp1+b_rpn) staged in LDS; 1x1 convs (54 ch) -> accum.
// ---------------------------------------------------------------------------
__global__ __launch_bounds__(256, 2) void k_post(const float* __restrict__ hp,
                                                 const float* __restrict__ br,
                                                 const float* __restrict__ wcl,
                                                 const float* __restrict__ wrg,
                                                 const float* __restrict__ bcl,
                                                 const float* __restrict__ brg,
                                                 float* __restrict__ accum) {
    __shared__ float hsm[24 * 520];
    __shared__ float wcs[54 * 130];
    const int tid = threadIdx.x;
    const int gp0 = blockIdx.x * 24;

    for (int i = tid; i < 24 * 512; i += 256) {
        int px = i >> 9, ci = i & 511;
        int cbk = ci >> 7, co = ci & 127;
        size_t off = ((size_t)cbk * NPIX + gp0 + px) * 128 + co;
        float v = hp[off] + hp[off + HP_HALF] + br[ci];
        hsm[px * 520 + ci] = fmaxf(v, 0.f);
    }

    const int px  = tid >> 3;
    const int chb = tid & 7;
    float part[7];
#pragma unroll
    for (int k = 0; k < 7; ++k) part[k] = 0.f;

    for (int chunk = 0; chunk < 4; ++chunk) {
        __syncthreads();
        for (int i = tid; i < 54 * 128; i += 256) {
            int ch = i >> 7, j = i & 127;
            wcs[ch * 130 + j] = (ch < 18) ? wcl[ch * 512 + chunk * 128 + j]
                                          : wrg[(ch - 18) * 512 + chunk * 128 + j];
        }
        __syncthreads();
        if (px < 24) {
            const float4* hv = (const float4*)(hsm + px * 520 + chunk * 128);
#pragma unroll 4
            for (int q = 0; q < 32; ++q) {
                float4 hq = hv[q];
#pragma unroll
                for (int k = 0; k < 7; ++k) {
                    int ch = chb * 7 + k;
                    if (ch < 54) {
                        float4 wq = *(const float4*)(wcs + ch * 130 + q * 4);
                        part[k] += hq.x * wq.x + hq.y * wq.y + hq.z * wq.z + hq.w * wq.w;
                    }
                }
            }
        }
    }
    if (px < 24) {
#pragma unroll
        for (int k = 0; k < 7; ++k) {
            int ch = chb * 7 + k;
            if (ch < 54) {
                float b = (ch < 18) ? bcl[ch] : brg[ch - 18];
                accum[(size_t)(gp0 + px) * NCH + ch] = part[k] + b;
            }
        }
    }
}

// ---------------------------------------------------------------------------
// decode: anchors + reg -> proposals/clipped boxes; cls -> d = c1-c0; histogram
// ---------------------------------------------------------------------------
__device__ __forceinline__ unsigned int key_of(float d) {
    unsigned int u = __float_as_uint(d);
    unsigned int k = (u & 0x80000000u) ? ~u : (u | 0x80000000u);  // asc in d
    return ~k;                                                     // asc key = desc d
}

__global__ void k_decode(const float* __restrict__ accum, const float* __restrict__ anchors,
                         float* __restrict__ props, float* __restrict__ boxes,
                         float* __restrict__ cls2, float* __restrict__ dval,
                         unsigned int* __restrict__ hist) {
    int idx = blockIdx.x * 256 + threadIdx.x;
    if (idx >= NA) return;
    int p = idx / 9, a = idx - p * 9;
    const float* ac = accum + p * NCH;
    float c0 = ac[2 * a], c1 = ac[2 * a + 1];
    float r0 = ac[18 + 4 * a + 0], r1 = ac[18 + 4 * a + 1];
    float r2 = ac[18 + 4 * a + 2], r3 = ac[18 + 4 * a + 3];
    const float* A = anchors + (size_t)idx * 4;
    float aw = A[2] - A[0] + 1.f, ah = A[3] - A[1] + 1.f;
    float ax = A[0] + 0.5f * (aw - 1.f), ay = A[1] + 0.5f * (ah - 1.f);
    float px = ax + aw * r0, py = ay + ah * r1;
    float pw = aw * expf(r2), ph = ah * expf(r3);
    float p0 = px - 0.5f * (pw - 1.f), p1 = py - 0.5f * (ph - 1.f);
    float p2 = px + 0.5f * (pw - 1.f), p3 = py + 0.5f * (ph - 1.f);
    props[idx * 4 + 0] = p0; props[idx * 4 + 1] = p1;
    props[idx * 4 + 2] = p2; props[idx * 4 + 3] = p3;
    boxes[idx * 4 + 0] = fminf(fmaxf(p0, 0.f), (float)(1536 - 1));
    boxes[idx * 4 + 1] = fminf(fmaxf(p1, 0.f), (float)(1536 - 1));
    boxes[idx * 4 + 2] = fminf(fmaxf(p2, 0.f), (float)(1536 - 1));
    boxes[idx * 4 + 3] = fminf(fmaxf(p3, 0.f), (float)(1536 - 1));
    cls2[idx * 2 + 0] = c0; cls2[idx * 2 + 1] = c1;
    float d = c1 - c0;
    dval[idx] = d;
    atomicAdd(&hist[key_of(d) >> 16], 1u);
}

// ---------------------------------------------------------------------------
// threshold: find histogram bin T containing rank-6000. 1024 threads,
// coalesced reads + LDS-atomic super-bins.
// ---------------------------------------------------------------------------
__global__ __launch_bounds__(1024) void k_thresh(const unsigned int* __restrict__ hist,
                                                 unsigned int* __restrict__ ctrl) {
    __shared__ unsigned int s[256];
    __shared__ unsigned int ss[256];
    __shared__ unsigned int chunkIdx, baseCount;
    const int tid = threadIdx.x;
    if (tid < 256) s[tid] = 0u;
    __syncthreads();
    for (int i = tid; i < 65536; i += 1024)
        atomicAdd(&s[i >> 8], hist[i]);
    __syncthreads();
    if (tid == 0) {
        unsigned int cum = 0; int c = 0;
        for (; c < 256; ++c) { if (cum + s[c] >= TOPN) break; cum += s[c]; }
        chunkIdx = (unsigned int)c; baseCount = cum;
    }
    __syncthreads();
    if (tid < 256) ss[tid] = hist[chunkIdx * 256 + tid];
    __syncthreads();
    if (tid == 0) {
        unsigned int cum = baseCount; int b = 0;
        for (; b < 256; ++b) { cum += ss[b]; if (cum >= TOPN) break; }
        ctrl[1] = chunkIdx * 256 + (unsigned int)b;  // T
        ctrl[2] = cum;
    }
}

// ---------------------------------------------------------------------------
// compact candidates (bin <= T): per-block LDS aggregation, 1 global atomic.
// ---------------------------------------------------------------------------
__global__ __launch_bounds__(256) void k_compact(const float* __restrict__ dval,
                                                 unsigned int* __restrict__ ctrl,
                                                 unsigned long long* __restrict__ cand) {
    __shared__ unsigned int cnt, base;
    const int tid = threadIdx.x;
    const int idx = blockIdx.x * 256 + tid;
    if (tid == 0) cnt = 0u;
    __syncthreads();
    unsigned int k2 = 0; bool pass = false; unsigned int pos = 0;
    if (idx < NA) {
        k2 = key_of(dval[idx]);
        pass = (k2 >> 16) <= ctrl[1];
        if (pass) pos = atomicAdd(&cnt, 1u);
    }
    __syncthreads();
    if (tid == 0) base = atomicAdd(&ctrl[0], cnt);
    __syncthreads();
    if (pass) {
        unsigned int p = base + pos;
        if (p < CAND_CAP) cand[p] = ((unsigned long long)k2 << 32) | (unsigned int)idx;
    }
}

// ---------------------------------------------------------------------------
// rank-by-count exact ordered top-6000 (cooperative shfl broadcast).
// ---------------------------------------------------------------------------
__global__ __launch_bounds__(256) void k_rank(const unsigned long long* __restrict__ cand,
                                              const unsigned int* __restrict__ ctrl,
                                              const float* __restrict__ boxes,
                                              const float* __restrict__ dval,
                                              float* __restrict__ topBoxes,
                                              float* __restrict__ topProbs) {
    __shared__ unsigned long long sc[CAND_CAP];   // 64 KB
    const int tid = threadIdx.x;
    unsigned int n = ctrl[0]; if (n > CAND_CAP) n = CAND_CAP;
    for (int i = tid; i < CAND_CAP; i += 256)
        sc[i] = (i < (int)n) ? cand[i] : 0xFFFFFFFFFFFFFFFFull;
    __syncthreads();
    const int i = blockIdx.x * 256 + tid;
    const unsigned long long mine = sc[i];
    const int l = tid & 63;
    const int nr = ((int)n + 63) & ~63;           // pads are MAX, never < mine
    int rank = 0;
    for (int j0 = 0; j0 < nr; j0 += 64) {
        unsigned long long kj = sc[j0 + l];
#pragma unroll
        for (int b = 0; b < 64; ++b) {
            unsigned long long kb = __shfl(kj, b);
            rank += (kb < mine) ? 1 : 0;
        }
    }
    if (i < (int)n && rank < TOPN) {
        unsigned int idx = (unsigned int)mine;
        ((float4*)topBoxes)[rank] = ((const float4*)boxes)[idx];
        topProbs[rank] = 1.f / (1.f + expf(-dval[idx]));
    }
}

// ---------------------------------------------------------------------------
// NMS suppression bitmask, triangular grid.
// ---------------------------------------------------------------------------
__global__ void k_mask(const float* __restrict__ topBoxes, unsigned long long* __restrict__ mask) {
    const int c = blockIdx.y;
    const int i = blockIdx.x * 256 + threadIdx.x;
    if (i >= TOPN || c < (i >> 6)) return;
    float4 bi = ((const float4*)topBoxes)[i];
    float ai = (bi.z - bi.x + 1.f) * (bi.w - bi.y + 1.f);
    unsigned long long m = 0;
    int j0 = c * 64;
    for (int b = 0; b < 64; ++b) {
        int j = j0 + b;
        if (j >= TOPN || j <= i) continue;
        float4 bj = ((const float4*)topBoxes)[j];
        float aj = (bj.z - bj.x + 1.f) * (bj.w - bj.y + 1.f);
        float iw = fmaxf(fminf(bi.z, bj.z) - fmaxf(bi.x, bj.x) + 1.f, 0.f);
        float ih = fmaxf(fminf(bi.w, bj.w) - fmaxf(bi.y, bj.y) + 1.f, 0.f);
        float inter = iw * ih;
        float iou = inter / (ai + aj - inter);
        if (iou > 0.7f) m |= (1ull << b);
    }
    mask[(size_t)i * NW + c] = m;
}

// ---------------------------------------------------------------------------
// greedy scan, single wave, batched unconditional loads, early exit at 300.
// ---------------------------------------------------------------------------
__global__ __launch_bounds__(64) void k_scan(const unsigned long long* __restrict__ mask,
                                             const float* __restrict__ topBoxes,
                                             const float* __restrict__ topProbs,
                                             float* __restrict__ out2, float* __restrict__ out3) {
    __shared__ unsigned long long kw[NW];
    int l = threadIdx.x;
    for (int i = l; i < NW; i += 64)
        kw[i] = (i == NW - 1) ? 0x0000FFFFFFFFFFFFull : ~0ull;  // 6000 = 93*64+48
    __syncthreads();
    int kept = 0;
    for (int c = 0; c < NW && kept < POSN; ++c) {
        unsigned long long w = kw[c];
        unsigned long long m = mask[(size_t)(c * 64 + l) * NW + c];
        for (int b = 0; b < 64; ++b) {
            if ((w >> b) & 1ull) {
                unsigned long long mb = __shfl(m, b);
                w &= ~mb;
            }
        }
        if ((w >> l) & 1ull) {
            int r = kept + __popcll(w & ((1ull << l) - 1ull));
            if (r < POSN) {
                int j = c * 64 + l;
                out2[r * 4 + 0] = topBoxes[j * 4 + 0];
                out2[r * 4 + 1] = topBoxes[j * 4 + 1];
                out2[r * 4 + 2] = topBoxes[j * 4 + 2];
                out2[r * 4 + 3] = topBoxes[j * 4 + 3];
                out3[r] = topProbs[j];
            }
        }
        kept += __popcll(w);
        if (kept >= POSN) break;
        for (int c2 = c + 1 + l; c2 < NW; c2 += 64) {
            unsigned long long sup = 0;
#pragma unroll
            for (int b0 = 0; b0 < 64; b0 += 16) {
                unsigned long long t[16];
#pragma unroll
                for (int j = 0; j < 16; ++j)
                    t[j] = mask[(size_t)(c * 64 + b0 + j) * NW + c2];
#pragma unroll
                for (int j = 0; j < 16; ++j)
                    sup |= ((w >> (b0 + j)) & 1ull) ? t[j] : 0ull;
            }
            kw[c2] &= ~sup;
        }
        __syncthreads();
    }
    for (int r = kept + l; r < POSN; r += 64) {
        out2[r * 4 + 0] = 0.f; out2[r * 4 + 1] = 0.f;
        out2[r * 4 + 2] = 0.f; out2[r * 4 + 3] = 0.f;
        out3[r] = 0.f;
    }
}

// ---------------------------------------------------------------------------
// gather proposals/cls at valid_idx
// ---------------------------------------------------------------------------
__global__ void k_gather(const int* __restrict__ vidx, const float* __restrict__ props,
                         const float* __restrict__ cls2, float* __restrict__ out0,
                         float* __restrict__ out1, int nv) {
    int i = blockIdx.x * 256 + threadIdx.x;
    if (i >= nv) return;
    int v = vidx[i];
    ((float4*)out0)[i] = ((const float4*)props)[v];
    ((float2*)out1)[i] = ((const float2*)cls2)[v];
}

// ---------------------------------------------------------------------------
extern "C" void kernel_launch(void* const* d_in, const int* in_sizes, int n_in,
                              void* d_out, int out_size, void* d_ws, size_t ws_size,
                              hipStream_t stream) {
    const float* x       = (const float*)d_in[0];
    const float* w_rpn   = (const float*)d_in[1];
    const float* b_rpn   = (const float*)d_in[2];
    const float* w_cls   = (const float*)d_in[3];
    const float* b_cls   = (const float*)d_in[4];
    const float* w_reg   = (const float*)d_in[5];
    const float* b_reg   = (const float*)d_in[6];
    const float* anchors = (const float*)d_in[7];
    const int*   vidx    = (const int*)d_in[8];
    const int nv = in_sizes[8];

    char* ws = (char*)d_ws;
    float* accum            = (float*)(ws + 0);
    float* props            = (float*)(ws + 1990656);
    float* boxes            = (float*)(ws + 3317760);
    float* cls2             = (float*)(ws + 4644864);
    float* dval             = (float*)(ws + 5308416);
    unsigned int* hist      = (unsigned int*)(ws + 5640192);
    unsigned int* ctrl      = (unsigned int*)(ws + 5902336);
    unsigned long long* cand = (unsigned long long*)(ws + 5902400);
    float* topBoxes         = (float*)(ws + 5967936);
    float* topProbs         = (float*)(ws + 6063936);
    unsigned long long* mask = (unsigned long long*)(ws + 6087936);  // 4.512 MB
    _Float16* xt_h          = (_Float16*)(ws + 10599936);  // 18.87 MB
    _Float16* xt_l          = (_Float16*)(ws + 29474304);  // 18.87 MB
    _Float16* wt2           = (_Float16*)(ws + 48348672);  // 18.87 MB fragment-ordered
    float* hp               = (float*)(ws + 67223040);     // 37.75 MB (ends ~105 MB)

    float* out0 = (float*)d_out;
    float* out1 = out0 + (size_t)nv * 4;
    float* out2 = out1 + (size_t)nv * 2;
    float* out3 = out2 + (size_t)POSN * 4;

    k_init<<<(65536 + 16 + 255) / 256, 256, 0, stream>>>(hist, ctrl);
    k_xtr<<<dim3(144, 16), 256, 0, stream>>>(x, xt_h, xt_l);
    k_wtr<<<dim3(4, 32), 256, 0, stream>>>(w_rpn, wt2);
    k_conv<<<dim3(4, 96, 2), 256, 0, stream>>>(xt_h, xt_l, wt2, hp);
    k_post<<<384, 256, 0, stream>>>(hp, b_rpn, w_cls, w_reg, b_cls, b_reg, accum);
    k_decode<<<(NA + 255) / 256, 256, 0, stream>>>(accum, anchors, props, boxes, cls2, dval, hist);
    k_thresh<<<1, 1024, 0, stream>>>(hist, ctrl);
    k_compact<<<(NA + 255) / 256, 256, 0, stream>>>(dval, ctrl, cand);
    k_rank<<<32, 256, 0, stream>>>(cand, ctrl, boxes, dval, topBoxes, topProbs);
    k_mask<<<dim3(24, NW), 256, 0, stream>>>(topBoxes, mask);
    k_scan<<<1, 64, 0, stream>>>(mask, topBoxes, topProbs, out2, out3);
    k_gather<<<(nv + 255) / 256, 256, 0, stream>>>(vidx, props, cls2, out0, out1, nv);
}

// Round 10
// 764.918 us; speedup vs baseline: 1.4347x; 1.4347x over previous
//
#include <hip/hip_runtime.h>

#define H 96
#define W 96
#define CIN 1024
#define NPIX 9216          // 96*96
#define NCH 54             // 18 cls + 36 reg channels
#define NA 82944           // 9216*9 anchors
#define TOPN 6000
#define NW 94              // ceil(6000/64)
#define POSN 300
#define CAND_CAP 8192

typedef _Float16 half8_t __attribute__((ext_vector_type(8)));
typedef float f32x4 __attribute__((ext_vector_type(4)));

#define CIP 40             // padded ci stride in halves (80 B: 16B-aligned, 2-way banks = free)
#define XS_PLANE 11760     // 3*98*40 halves
#define HP_HALF 4718592    // 4*9216*128 floats per K-split buffer

// ---------------------------------------------------------------------------
// init: hist/ctrl <- 0
// ---------------------------------------------------------------------------
__global__ void k_init(unsigned int* __restrict__ hist, unsigned int* __restrict__ ctrl) {
    int t = blockIdx.x * 256 + threadIdx.x;
    if (t < 65536) hist[t] = 0u;
    else if (t < 65536 + 16) ctrl[t - 65536] = 0u;
}

// ---------------------------------------------------------------------------
// x transpose + fp16 split: x[ci][px] fp32 -> xt_h[px][ci], xt_l[px][ci]
// half8 (16B/lane) vectorized stores.
// ---------------------------------------------------------------------------
__global__ __launch_bounds__(256) void k_xtr(const float* __restrict__ x,
                                             _Float16* __restrict__ xh,
                                             _Float16* __restrict__ xl) {
    __shared__ float t[64 * 65];
    const int tid = threadIdx.x;
    const int px0 = blockIdx.x * 64, ci0 = blockIdx.y * 64;
    for (int i = tid; i < 4096; i += 256) {
        int ci = i >> 6, px = i & 63;
        t[ci * 65 + px] = x[(size_t)(ci0 + ci) * NPIX + px0 + px];
    }
    __syncthreads();
    for (int i = tid; i < 512; i += 256) {     // 64 px x 8 ci-octets
        int px = i >> 3, q = i & 7;
        _Float16 h8[8], l8[8];
#pragma unroll
        for (int j = 0; j < 8; ++j) {
            float v = t[(q * 8 + j) * 65 + px];
            _Float16 h = (_Float16)v;
            h8[j] = h;
            l8[j] = (_Float16)((v - (float)h) * 2048.f);
        }
        size_t o = (size_t)(px0 + px) * 1024 + ci0 + q * 8;
        *(half8_t*)(xh + o) = *(half8_t*)h8;
        *(half8_t*)(xl + o) = *(half8_t*)l8;
    }
}

// ---------------------------------------------------------------------------
// weight transform to MFMA-fragment order + fp16 split (coalesced).
// ---------------------------------------------------------------------------
__global__ __launch_bounds__(256) void k_wtr(const float* __restrict__ wr,
                                             _Float16* __restrict__ wt2) {
    __shared__ float tile[32 * 292];
    const int cb = blockIdx.x, cc = blockIdx.y;
    const int tid = threadIdx.x;
    for (int g = 0; g < 4; ++g) {
        __syncthreads();
        for (int i = tid; i < 32 * 288; i += 256) {
            int row = i / 288, col = i - row * 288;
            tile[row * 292 + col] = wr[(size_t)(cb * 128 + g * 32 + row) * 9216 + cc * 288 + col];
        }
        __syncthreads();
#pragma unroll
        for (int k = 0; k < 9; ++k) {
            int G = k * 256 + tid;           // < 2304
            int tap = G >> 8, r = G & 255;
            int pl = r >> 7, ntl = (r >> 6) & 1, l = r & 63;
            int co_loc = ntl * 16 + (l & 15);
            int ci_b = (l >> 4) * 8;
            _Float16 o8[8];
#pragma unroll
            for (int j = 0; j < 8; ++j) {
                float v = tile[co_loc * 292 + (ci_b + j) * 9 + tap];
                _Float16 h = (_Float16)v;
                o8[j] = pl ? (_Float16)((v - (float)h) * 2048.f) : h;
            }
            _Float16* dst = wt2 + ((size_t)((tap * 4 + cb) * 32 + cc)) * 8192 +
                            (size_t)(pl * 8 + (g * 2 + ntl)) * 512 + l * 8;
            *(half8_t*)dst = *(half8_t*)o8;
        }
    }
}

// ---------------------------------------------------------------------------
// MFMA implicit-GEMM conv3x3(1024->512), K-split by 2.  [R8 structure]
// fp16 2-plane split: h = Ah*Bh + (Ah*Bl' + Al'*Bh)/2048.
// Block = 1 row (96 px) x 128 co, 4 waves; wave = 3 m-tiles x 4 n-tiles.
// B direct from global (fragment-ordered wt2), prefetched one tap ahead;
// x register-prefetched one chunk ahead. 2 blocks/CU.
// Y-BAND XCD SWIZZLE: 1D grid 768; with round-robin bid%8 -> XCD dispatch,
// XCD k gets rows [12k,12k+12) for ALL (cb,ks): x slice ~5 MB streams once,
// and the ~64 co-paced resident blocks keep the instantaneous B footprint
// (~8 combos x ~2 cc x 9 taps x 16 KB ~= 2.3 MB) inside the 4 MB L2.
// ---------------------------------------------------------------------------
__global__ __launch_bounds__(256, 2) void k_conv(
    const _Float16* __restrict__ xth, const _Float16* __restrict__ xtl,
    const _Float16* __restrict__ wt2, float* __restrict__ hp) {
    __shared__ __align__(16) char smem[49408];   // xs 47040 B; epilogue 96x128 f32
    _Float16* xs = (_Float16*)smem;

    const int tid = threadIdx.x;
    const int bid = blockIdx.x;
    const int xcd = bid & 7;
    const int i8  = bid >> 3;          // 0..95
    const int y   = xcd * 12 + (i8 % 12);
    const int cbks = i8 / 12;          // 0..7
    const int cb  = cbks & 3;          // co block of 128
    const int ks  = cbks >> 2;         // K-split half
    const int l  = tid & 63;
    const int wv = tid >> 6;          // 0..3
    const int mg = wv & 1;            // m-group
    const int ng = wv >> 1;           // n-group
    const int lm = l & 15;
    const int lk = l >> 4;            // 0..3

    f32x4 acc_h[3][4];
    f32x4 acc_x[3][4];
#pragma unroll
    for (int m2 = 0; m2 < 3; ++m2)
#pragma unroll
        for (int nt = 0; nt < 4; ++nt) {
            acc_h[m2][nt] = (f32x4){0.f, 0.f, 0.f, 0.f};
            acc_x[m2][nt] = (f32x4){0.f, 0.f, 0.f, 0.f};
        }

    // zero px pad columns (pxp = 0 and 97), both planes, 3 rows
    for (int i = tid; i < 480; i += 256) {
        int pl = i / 240, j = i - pl * 240;
        int r = j / 80, j2 = j - r * 80;
        int side = j2 / 40, c = j2 - side * 40;
        xs[pl * XS_PLANE + (r * 98 + side * 97) * CIP + c] = (_Float16)0.f;
    }

    auto ldx = [&](float4* xr, int cc_) {
#pragma unroll
        for (int k = 0; k < 9; ++k) {
            int item = k * 256 + tid;
            int pl = (item >= 1152) ? 1 : 0;
            int j = item - pl * 1152;
            int r = j / 384, j2 = j - r * 384;
            int px = j2 >> 2, q = j2 & 3;
            int yy = y + r - 1;
            float4 v = {0.f, 0.f, 0.f, 0.f};
            if (yy >= 0 && yy < H)
                v = *(const float4*)((pl ? xtl : xth) + (size_t)(yy * 96 + px) * 1024 + cc_ * 32 + q * 8);
            xr[k] = v;
        }
    };
    auto stx = [&](const float4* xr) {
#pragma unroll
        for (int k = 0; k < 9; ++k) {
            int item = k * 256 + tid;
            int pl = (item >= 1152) ? 1 : 0;
            int j = item - pl * 1152;
            int r = j / 384, j2 = j - r * 384;
            int px = j2 >> 2, q = j2 & 3;
            *(float4*)(xs + pl * XS_PLANE + (r * 98 + px + 1) * CIP + q * 8) = xr[k];
        }
    };
    auto ldb = [&](half8_t* bh, half8_t* bl, int cc_, int tap_) {
        const _Float16* base = wt2 + ((size_t)((tap_ * 4 + cb) * 32 + cc_) * 16) * 512 + (size_t)l * 8;
#pragma unroll
        for (int nt = 0; nt < 4; ++nt) {
            bh[nt] = *(const half8_t*)(base + (size_t)(ng * 4 + nt) * 512);
            bl[nt] = *(const half8_t*)(base + (size_t)(8 + ng * 4 + nt) * 512);
        }
    };

    const int cc0 = ks * 16;
    float4 xr[9];
    ldx(xr, cc0);
    half8_t bnh[4], bnl[4];
    ldb(bnh, bnl, cc0, 0);

    for (int cc = cc0; cc < cc0 + 16; ++cc) {
        __syncthreads();           // previous chunk's xs reads complete
        stx(xr);
        __syncthreads();           // xs visible
        const int ccn = (cc + 1 < 32) ? cc + 1 : cc;
        ldx(xr, ccn);              // prefetch next chunk's x (in flight during taps)

#pragma unroll
        for (int tap = 0; tap < 9; ++tap) {
            half8_t bh[4], bl[4];
#pragma unroll
            for (int nt = 0; nt < 4; ++nt) { bh[nt] = bnh[nt]; bl[nt] = bnl[nt]; }
            const int ntap = (tap == 8) ? 0 : tap + 1;
            const int ncc  = (tap == 8) ? ccn : cc;
            ldb(bnh, bnl, ncc, ntap);   // prefetch next tap's B

            const int ky = tap / 3, kx = tap - 3 * (tap / 3);
            half8_t ah[3], al[3];
#pragma unroll
            for (int m2 = 0; m2 < 3; ++m2) {
                const int pxp = (mg * 3 + m2) * 16 + lm + kx;
                ah[m2] = *(const half8_t*)(xs + (ky * 98 + pxp) * CIP + lk * 8);
                al[m2] = *(const half8_t*)(xs + XS_PLANE + (ky * 98 + pxp) * CIP + lk * 8);
            }
#pragma unroll
            for (int m2 = 0; m2 < 3; ++m2)
#pragma unroll
                for (int nt = 0; nt < 4; ++nt)
                    acc_h[m2][nt] = __builtin_amdgcn_mfma_f32_16x16x32_f16(ah[m2], bh[nt], acc_h[m2][nt], 0, 0, 0);
#pragma unroll
            for (int m2 = 0; m2 < 3; ++m2)
#pragma unroll
                for (int nt = 0; nt < 4; ++nt)
                    acc_x[m2][nt] = __builtin_amdgcn_mfma_f32_16x16x32_f16(ah[m2], bl[nt], acc_x[m2][nt], 0, 0, 0);
#pragma unroll
            for (int m2 = 0; m2 < 3; ++m2)
#pragma unroll
                for (int nt = 0; nt < 4; ++nt)
                    acc_x[m2][nt] = __builtin_amdgcn_mfma_f32_16x16x32_f16(al[m2], bh[nt], acc_x[m2][nt], 0, 0, 0);
        }
    }

    // ---- epilogue: combine planes, bounce through LDS, coalesced store ----
    __syncthreads();
    float* cs = (float*)smem;
#pragma unroll
    for (int m2 = 0; m2 < 3; ++m2)
#pragma unroll
        for (int nt = 0; nt < 4; ++nt) {
            int co = (ng * 4 + nt) * 16 + lm;
#pragma unroll
            for (int r = 0; r < 4; ++r) {
                int px = (mg * 3 + m2) * 16 + lk * 4 + r;
                cs[px * 128 + co] = acc_h[m2][nt][r] + acc_x[m2][nt][r] * (1.f / 2048.f);
            }
        }
    __syncthreads();
    float4* dst = (float4*)(hp + ((size_t)(ks * 4 + cb) * NPIX + y * 96) * 128);
    const float4* src = (const float4*)cs;
    for (int i = tid; i < 3072; i += 256) dst[i] = src[i];
}

// ---------------------------------------------------------------------------
// post: h = relu(hp0+hp1+b_rpn) staged in LDS; 1x1 convs (54 ch) -> accum.
// ---------------------------------------------------------------------------
__global__ __launch_bounds__(256, 2) void k_post(const float* __restrict__ hp,
                                                 const float* __restrict__ br,
                                                 const float* __restrict__ wcl,
                                                 const float* __restrict__ wrg,
                                                 const float* __restrict__ bcl,
                                                 const float* __restrict__ brg,
                                                 float* __restrict__ accum) {
    __shared__ float hsm[24 * 520];
    __shared__ float wcs[54 * 130];
    const int tid = threadIdx.x;
    const int gp0 = blockIdx.x * 24;

    for (int i = tid; i < 24 * 512; i += 256) {
        int px = i >> 9, ci = i & 511;
        int cbk = ci >> 7, co = ci & 127;
        size_t off = ((size_t)cbk * NPIX + gp0 + px) * 128 + co;
        float v = hp[off] + hp[off + HP_HALF] + br[ci];
        hsm[px * 520 + ci] = fmaxf(v, 0.f);
    }

    const int px  = tid >> 3;
    const int chb = tid & 7;
    float part[7];
#pragma unroll
    for (int k = 0; k < 7; ++k) part[k] = 0.f;

    for (int chunk = 0; chunk < 4; ++chunk) {
        __syncthreads();
        for (int i = tid; i < 54 * 128; i += 256) {
            int ch = i >> 7, j = i & 127;
            wcs[ch * 130 + j] = (ch < 18) ? wcl[ch * 512 + chunk * 128 + j]
                                          : wrg[(ch - 18) * 512 + chunk * 128 + j];
        }
        __syncthreads();
        if (px < 24) {
            const float4* hv = (const float4*)(hsm + px * 520 + chunk * 128);
#pragma unroll 4
            for (int q = 0; q < 32; ++q) {
                float4 hq = hv[q];
#pragma unroll
                for (int k = 0; k < 7; ++k) {
                    int ch = chb * 7 + k;
                    if (ch < 54) {
                        float4 wq = *(const float4*)(wcs + ch * 130 + q * 4);
                        part[k] += hq.x * wq.x + hq.y * wq.y + hq.z * wq.z + hq.w * wq.w;
                    }
                }
            }
        }
    }
    if (px < 24) {
#pragma unroll
        for (int k = 0; k < 7; ++k) {
            int ch = chb * 7 + k;
            if (ch < 54) {
                float b = (ch < 18) ? bcl[ch] : brg[ch - 18];
                accum[(size_t)(gp0 + px) * NCH + ch] = part[k] + b;
            }
        }
    }
}

// ---------------------------------------------------------------------------
// decode: anchors + reg -> proposals/clipped boxes; cls -> d = c1-c0; histogram
// ---------------------------------------------------------------------------
__device__ __forceinline__ unsigned int key_of(float d) {
    unsigned int u = __float_as_uint(d);
    unsigned int k = (u & 0x80000000u) ? ~u : (u | 0x80000000u);  // asc in d
    return ~k;                                                     // asc key = desc d
}

__global__ void k_decode(const float* __restrict__ accum, const float* __restrict__ anchors,
                         float* __restrict__ props, float* __restrict__ boxes,
                         float* __restrict__ cls2, float* __restrict__ dval,
                         unsigned int* __restrict__ hist) {
    int idx = blockIdx.x * 256 + threadIdx.x;
    if (idx >= NA) return;
    int p = idx / 9, a = idx - p * 9;
    const float* ac = accum + p * NCH;
    float c0 = ac[2 * a], c1 = ac[2 * a + 1];
    float r0 = ac[18 + 4 * a + 0], r1 = ac[18 + 4 * a + 1];
    float r2 = ac[18 + 4 * a + 2], r3 = ac[18 + 4 * a + 3];
    const float* A = anchors + (size_t)idx * 4;
    float aw = A[2] - A[0] + 1.f, ah = A[3] - A[1] + 1.f;
    float ax = A[0] + 0.5f * (aw - 1.f), ay = A[1] + 0.5f * (ah - 1.f);
    float px = ax + aw * r0, py = ay + ah * r1;
    float pw = aw * expf(r2), ph = ah * expf(r3);
    float p0 = px - 0.5f * (pw - 1.f), p1 = py - 0.5f * (ph - 1.f);
    float p2 = px + 0.5f * (pw - 1.f), p3 = py + 0.5f * (ph - 1.f);
    props[idx * 4 + 0] = p0; props[idx * 4 + 1] = p1;
    props[idx * 4 + 2] = p2; props[idx * 4 + 3] = p3;
    boxes[idx * 4 + 0] = fminf(fmaxf(p0, 0.f), (float)(1536 - 1));
    boxes[idx * 4 + 1] = fminf(fmaxf(p1, 0.f), (float)(1536 - 1));
    boxes[idx * 4 + 2] = fminf(fmaxf(p2, 0.f), (float)(1536 - 1));
    boxes[idx * 4 + 3] = fminf(fmaxf(p3, 0.f), (float)(1536 - 1));
    cls2[idx * 2 + 0] = c0; cls2[idx * 2 + 1] = c1;
    float d = c1 - c0;
    dval[idx] = d;
    atomicAdd(&hist[key_of(d) >> 16], 1u);
}

// ---------------------------------------------------------------------------
// threshold: find histogram bin T containing rank-6000. 1024 threads,
// coalesced reads + LDS-atomic super-bins.
// ---------------------------------------------------------------------------
__global__ __launch_bounds__(1024) void k_thresh(const unsigned int* __restrict__ hist,
                                                 unsigned int* __restrict__ ctrl) {
    __shared__ unsigned int s[256];
    __shared__ unsigned int ss[256];
    __shared__ unsigned int chunkIdx, baseCount;
    const int tid = threadIdx.x;
    if (tid < 256) s[tid] = 0u;
    __syncthreads();
    for (int i = tid; i < 65536; i += 1024)
        atomicAdd(&s[i >> 8], hist[i]);
    __syncthreads();
    if (tid == 0) {
        unsigned int cum = 0; int c = 0;
        for (; c < 256; ++c) { if (cum + s[c] >= TOPN) break; cum += s[c]; }
        chunkIdx = (unsigned int)c; baseCount = cum;
    }
    __syncthreads();
    if (tid < 256) ss[tid] = hist[chunkIdx * 256 + tid];
    __syncthreads();
    if (tid == 0) {
        unsigned int cum = baseCount; int b = 0;
        for (; b < 256; ++b) { cum += ss[b]; if (cum >= TOPN) break; }
        ctrl[1] = chunkIdx * 256 + (unsigned int)b;  // T
        ctrl[2] = cum;
    }
}

// ---------------------------------------------------------------------------
// compact candidates (bin <= T): per-block LDS aggregation, 1 global atomic.
// ---------------------------------------------------------------------------
__global__ __launch_bounds__(256) void k_compact(const float* __restrict__ dval,
                                                 unsigned int* __restrict__ ctrl,
                                                 unsigned long long* __restrict__ cand) {
    __shared__ unsigned int cnt, base;
    const int tid = threadIdx.x;
    const int idx = blockIdx.x * 256 + tid;
    if (tid == 0) cnt = 0u;
    __syncthreads();
    unsigned int k2 = 0; bool pass = false; unsigned int pos = 0;
    if (idx < NA) {
        k2 = key_of(dval[idx]);
        pass = (k2 >> 16) <= ctrl[1];
        if (pass) pos = atomicAdd(&cnt, 1u);
    }
    __syncthreads();
    if (tid == 0) base = atomicAdd(&ctrl[0], cnt);
    __syncthreads();
    if (pass) {
        unsigned int p = base + pos;
        if (p < CAND_CAP) cand[p] = ((unsigned long long)k2 << 32) | (unsigned int)idx;
    }
}

// ---------------------------------------------------------------------------
// rank-by-count exact ordered top-6000 (cooperative shfl broadcast).
// ---------------------------------------------------------------------------
__global__ __launch_bounds__(256) void k_rank(const unsigned long long* __restrict__ cand,
                                              const unsigned int* __restrict__ ctrl,
                                              const float* __restrict__ boxes,
                                              const float* __restrict__ dval,
                                              float* __restrict__ topBoxes,
                                              float* __restrict__ topProbs) {
    __shared__ unsigned long long sc[CAND_CAP];   // 64 KB
    const int tid = threadIdx.x;
    unsigned int n = ctrl[0]; if (n > CAND_CAP) n = CAND_CAP;
    for (int i = tid; i < CAND_CAP; i += 256)
        sc[i] = (i < (int)n) ? cand[i] : 0xFFFFFFFFFFFFFFFFull;
    __syncthreads();
    const int i = blockIdx.x * 256 + tid;
    const unsigned long long mine = sc[i];
    const int l = tid & 63;
    const int nr = ((int)n + 63) & ~63;           // pads are MAX, never < mine
    int rank = 0;
    for (int j0 = 0; j0 < nr; j0 += 64) {
        unsigned long long kj = sc[j0 + l];
#pragma unroll
        for (int b = 0; b < 64; ++b) {
            unsigned long long kb = __shfl(kj, b);
            rank += (kb < mine) ? 1 : 0;
        }
    }
    if (i < (int)n && rank < TOPN) {
        unsigned int idx = (unsigned int)mine;
        ((float4*)topBoxes)[rank] = ((const float4*)boxes)[idx];
        topProbs[rank] = 1.f / (1.f + expf(-dval[idx]));
    }
}

// ---------------------------------------------------------------------------
// NMS suppression bitmask, triangular grid.
// ---------------------------------------------------------------------------
__global__ void k_mask(const float* __restrict__ topBoxes, unsigned long long* __restrict__ mask) {
    const int c = blockIdx.y;
    const int i = blockIdx.x * 256 + threadIdx.x;
    if (i >= TOPN || c < (i >> 6)) return;
    float4 bi = ((const float4*)topBoxes)[i];
    float ai = (bi.z - bi.x + 1.f) * (bi.w - bi.y + 1.f);
    unsigned long long m = 0;
    int j0 = c * 64;
    for (int b = 0; b < 64; ++b) {
        int j = j0 + b;
        if (j >= TOPN || j <= i) continue;
        float4 bj = ((const float4*)topBoxes)[j];
        float aj = (bj.z - bj.x + 1.f) * (bj.w - bj.y + 1.f);
        float iw = fmaxf(fminf(bi.z, bj.z) - fmaxf(bi.x, bj.x) + 1.f, 0.f);
        float ih = fmaxf(fminf(bi.w, bj.w) - fmaxf(bi.y, bj.y) + 1.f, 0.f);
        float inter = iw * ih;
        float iou = inter / (ai + aj - inter);
        if (iou > 0.7f) m |= (1ull << b);
    }
    mask[(size_t)i * NW + c] = m;
}

// ---------------------------------------------------------------------------
// greedy scan, single wave, batched unconditional loads, early exit at 300.
// ---------------------------------------------------------------------------
__global__ __launch_bounds__(64) void k_scan(const unsigned long long* __restrict__ mask,
                                             const float* __restrict__ topBoxes,
                                             const float* __restrict__ topProbs,
                                             float* __restrict__ out2, float* __restrict__ out3) {
    __shared__ unsigned long long kw[NW];
    int l = threadIdx.x;
    for (int i = l; i < NW; i += 64)
        kw[i] = (i == NW - 1) ? 0x0000FFFFFFFFFFFFull : ~0ull;  // 6000 = 93*64+48
    __syncthreads();
    int kept = 0;
    for (int c = 0; c < NW && kept < POSN; ++c) {
        unsigned long long w = kw[c];
        unsigned long long m = mask[(size_t)(c * 64 + l) * NW + c];
        for (int b = 0; b < 64; ++b) {
            if ((w >> b) & 1ull) {
                unsigned long long mb = __shfl(m, b);
                w &= ~mb;
            }
        }
        if ((w >> l) & 1ull) {
            int r = kept + __popcll(w & ((1ull << l) - 1ull));
            if (r < POSN) {
                int j = c * 64 + l;
                out2[r * 4 + 0] = topBoxes[j * 4 + 0];
                out2[r * 4 + 1] = topBoxes[j * 4 + 1];
                out2[r * 4 + 2] = topBoxes[j * 4 + 2];
                out2[r * 4 + 3] = topBoxes[j * 4 + 3];
                out3[r] = topProbs[j];
            }
        }
        kept += __popcll(w);
        if (kept >= POSN) break;
        for (int c2 = c + 1 + l; c2 < NW; c2 += 64) {
            unsigned long long sup = 0;
#pragma unroll
            for (int b0 = 0; b0 < 64; b0 += 16) {
                unsigned long long t[16];
#pragma unroll
                for (int j = 0; j < 16; ++j)
                    t[j] = mask[(size_t)(c * 64 + b0 + j) * NW + c2];
#pragma unroll
                for (int j = 0; j < 16; ++j)
                    sup |= ((w >> (b0 + j)) & 1ull) ? t[j] : 0ull;
            }
            kw[c2] &= ~sup;
        }
        __syncthreads();
    }
    for (int r = kept + l; r < POSN; r += 64) {
        out2[r * 4 + 0] = 0.f; out2[r * 4 + 1] = 0.f;
        out2[r * 4 + 2] = 0.f; out2[r * 4 + 3] = 0.f;
        out3[r] = 0.f;
    }
}

// ---------------------------------------------------------------------------
// gather proposals/cls at valid_idx
// ---------------------------------------------------------------------------
__global__ void k_gather(const int* __restrict__ vidx, const float* __restrict__ props,
                         const float* __restrict__ cls2, float* __restrict__ out0,
                         float* __restrict__ out1, int nv) {
    int i = blockIdx.x * 256 + threadIdx.x;
    if (i >= nv) return;
    int v = vidx[i];
    ((float4*)out0)[i] = ((const float4*)props)[v];
    ((float2*)out1)[i] = ((const float2*)cls2)[v];
}

// ---------------------------------------------------------------------------
extern "C" void kernel_launch(void* const* d_in, const int* in_sizes, int n_in,
                              void* d_out, int out_size, void* d_ws, size_t ws_size,
                              hipStream_t stream) {
    const float* x       = (const float*)d_in[0];
    const float* w_rpn   = (const float*)d_in[1];
    const float* b_rpn   = (const float*)d_in[2];
    const float* w_cls   = (const float*)d_in[3];
    const float* b_cls   = (const float*)d_in[4];
    const float* w_reg   = (const float*)d_in[5];
    const float* b_reg   = (const float*)d_in[6];
    const float* anchors = (const float*)d_in[7];
    const int*   vidx    = (const int*)d_in[8];
    const int nv = in_sizes[8];

    char* ws = (char*)d_ws;
    float* accum            = (float*)(ws + 0);
    float* props            = (float*)(ws + 1990656);
    float* boxes            = (float*)(ws + 3317760);
    float* cls2             = (float*)(ws + 4644864);
    float* dval             = (float*)(ws + 5308416);
    unsigned int* hist      = (unsigned int*)(ws + 5640192);
    unsigned int* ctrl      = (unsigned int*)(ws + 5902336);
    unsigned long long* cand = (unsigned long long*)(ws + 5902400);
    float* topBoxes         = (float*)(ws + 5967936);
    float* topProbs         = (float*)(ws + 6063936);
    unsigned long long* mask = (unsigned long long*)(ws + 6087936);  // 4.512 MB
    _Float16* xt_h          = (_Float16*)(ws + 10599936);  // 18.87 MB
    _Float16* xt_l          = (_Float16*)(ws + 29474304);  // 18.87 MB
    _Float16* wt2           = (_Float16*)(ws + 48348672);  // 18.87 MB fragment-ordered
    float* hp               = (float*)(ws + 67223040);     // 37.75 MB (ends ~105 MB)

    float* out0 = (float*)d_out;
    float* out1 = out0 + (size_t)nv * 4;
    float* out2 = out1 + (size_t)nv * 2;
    float* out3 = out2 + (size_t)POSN * 4;

    k_init<<<(65536 + 16 + 255) / 256, 256, 0, stream>>>(hist, ctrl);
    k_xtr<<<dim3(144, 16), 256, 0, stream>>>(x, xt_h, xt_l);
    k_wtr<<<dim3(4, 32), 256, 0, stream>>>(w_rpn, wt2);
    k_conv<<<768, 256, 0, stream>>>(xt_h, xt_l, wt2, hp);
    k_post<<<384, 256, 0, stream>>>(hp, b_rpn, w_cls, w_reg, b_cls, b_reg, accum);
    k_decode<<<(NA + 255) / 256, 256, 0, stream>>>(accum, anchors, props, boxes, cls2, dval, hist);
    k_thresh<<<1, 1024, 0, stream>>>(hist, ctrl);
    k_compact<<<(NA + 255) / 256, 256, 0, stream>>>(dval, ctrl, cand);
    k_rank<<<32, 256, 0, stream>>>(cand, ctrl, boxes, dval, topBoxes, topProbs);
    k_mask<<<dim3(24, NW), 256, 0, stream>>>(topBoxes, mask);
    k_scan<<<1, 64, 0, stream>>>(mask, topBoxes, topProbs, out2, out3);
    k_gather<<<(nv + 255) / 256, 256, 0, stream>>>(vidx, props, cls2, out0, out1, nv);
}